// Round 6
// baseline (100.544 us; speedup 1.0000x reference)
//
#include <hip/hip_runtime.h>

namespace {

constexpr int S = 128;   // fine bins per row
constexpr int P = 64;    // proposal bins per row
constexpr int ROWS = 4;  // rows per wave
constexpr float EPS = 1.1920928955078125e-07f;  // np.finfo(np.float32).eps

// Crossbar read: value of `v` from lane (byteaddr/4 & 63). Conflict-free.
__device__ inline float bperm_f(int byteaddr, float v) {
    return __int_as_float(__builtin_amdgcn_ds_bpermute(byteaddr, __float_as_int(v)));
}

// v += dpp_permute(v); bound_ctrl=false, old=0 -> masked/invalid lanes add 0.
template <int CTRL, int ROW_MASK>
__device__ inline float dpp_add(float v) {
    int perm = __builtin_amdgcn_update_dpp(0, __float_as_int(v), CTRL, ROW_MASK, 0xf, false);
    return v + __int_as_float(perm);
}

template <int LANE>
__device__ inline float rdlane_f(float v) {
    return __int_as_float(__builtin_amdgcn_readlane(__float_as_int(v), LANE));
}

// One 64-lane wave per FOUR rows. All global loads for all 4 rows are issued
// up-front (max memory-level parallelism), then 4 independent compute chains.
// Per row: lane l holds th1 = t_hat[l+1], inc = cy1[l+1] (inclusive scan).
// lower_bound counts over inner edges t_hat[1..64]; t in (0,1) keeps lb in
// [1,64]. Byte convention: element i+1 (t_hat or cy1) at lane i -> byte 4i.
// Searches per lane: only t[2l], t[2l+1]. ub(t[2l+2]) comes from lane l+1's
// ub(t[2l]) via lane-shift; lane 63's t[128] via ballot+popcount.
__global__ __launch_bounds__(256) void proposal_loss_kernel(
    const float* __restrict__ t,      // [N, S+1]
    const float* __restrict__ w,      // [N, S]
    const float* __restrict__ t_hat,  // [N, P+1]
    const float* __restrict__ w_hat,  // [N, P]
    float* __restrict__ out)          // [N, S]
{
    const int wv   = threadIdx.x >> 6;
    const int lane = threadIdx.x & 63;
    const int row0 = (blockIdx.x << 2 | wv) * ROWS;

    float  th1[ROWS], wh[ROWS], tS[ROWS];
    float2 tt[ROWS], ww[ROWS];

    // ---- issue ALL loads first: ~4 KB of reads in flight per wave ----
    #pragma unroll
    for (int r = 0; r < ROWS; ++r) {
        const int row = row0 + r;
        const float* t_row  = t     + (size_t)row * (S + 1);
        const float* w_row  = w     + (size_t)row * S;
        const float* th_row = t_hat + (size_t)row * (P + 1);
        const float* wh_row = w_hat + (size_t)row * P;
        th1[r] = th_row[lane + 1];                              // t_hat[l+1]
        wh[r]  = wh_row[lane];
        tt[r]  = *reinterpret_cast<const float2*>(t_row + 2 * lane);
        ww[r]  = *reinterpret_cast<const float2*>(w_row + 2 * lane);
        tS[r]  = t_row[S];                                      // t[128], bcast
    }

    float2 res[ROWS];

    #pragma unroll
    for (int r = 0; r < ROWS; ++r) {
        // ---- inclusive scan of w_hat via DPP (VALU): inc(l) = cy1[l+1] ----
        float inc = wh[r];
        inc = dpp_add<0x111, 0xf>(inc);   // row_shr:1
        inc = dpp_add<0x112, 0xf>(inc);   // row_shr:2
        inc = dpp_add<0x114, 0xf>(inc);   // row_shr:4
        inc = dpp_add<0x118, 0xf>(inc);   // row_shr:8
        inc = dpp_add<0x142, 0xa>(inc);   // row_bcast:15 -> rows 1,3
        inc = dpp_add<0x143, 0xc>(inc);   // row_bcast:31 -> rows 2,3

        // ---- wave-uniform coarse table (SGPR): A[k]=t_hat[k+1] at lane k ----
        const float e31 = rdlane_f<31>(th1[r]);
        const float e15 = rdlane_f<15>(th1[r]);
        const float e47 = rdlane_f<47>(th1[r]);
        const float e7  = rdlane_f<7 >(th1[r]);
        const float e23 = rdlane_f<23>(th1[r]);
        const float e39 = rdlane_f<39>(th1[r]);
        const float e55 = rdlane_f<55>(th1[r]);

        // Branchless lower_bound: 3 coarse VALU levels + 3 fine ds_bpermute.
        // Returns posb = (lb-1)*4.
        auto lbb = [&](float v) {
            int posb = (e31 < v) ? 128 : 0;
            float l2 = posb ? e47 : e15;
            posb += (l2 < v) ? 64 : 0;
            float l3a = (posb & 128) ? e39 : e7;
            float l3b = (posb & 128) ? e55 : e23;
            float l3  = (posb & 64) ? l3b : l3a;
            posb += (l3 < v) ? 32 : 0;
            float p = bperm_f(posb + 12, th1[r]);  posb += (p < v) ? 16 : 0;
            p = bperm_f(posb + 4, th1[r]);         posb += (p < v) ? 8 : 0;
            p = bperm_f(posb, th1[r]);             posb += (p < v) ? 4 : 0;
            return posb;
        };

        const float t0  = tt[r].x;
        const float t1v = tt[r].y;
        const int b0 = lbb(t0);     // (lb(t[2l])-1)*4
        const int b1 = lbb(t1v);    // (lb(t[2l+1])-1)*4

        // Tie fixup via crossbar probe: ub = lb + (t_hat[lb] == v).
        const float p0 = bperm_f(b0, th1[r]);
        const float p1 = bperm_f(b1, th1[r]);
        const int u0b = b0 + ((p0 == t0)  ? 4 : 0);   // (ub(t0)-1)*4
        const int u1b = b1 + ((p1 == t1v) ? 4 : 0);   // (ub(t1)-1)*4

        // ub(t[2l+2]) = neighbor's ub(t0); lane 63 via ballot searchsorted:
        // ub(t[128]) byte = 4 * popc(t_hat[1..64] <= t[128]).
        int r2b = __shfl_down(u0b, 1, 64);
        const unsigned long long mS = __ballot(th1[r] <= tS[r]);
        const int pcb = (int)__popcll(mS) << 2;
        if (lane == 63) r2b = pcb;

        // cy1 gathers from the register-resident scan.
        const float cy_l0 = bperm_f(b0,  inc);   // cy1[lb(t0)]
        const float cy_l1 = bperm_f(b1,  inc);   // cy1[lb(t1)]
        const float cy_h0 = bperm_f(u1b, inc);   // cy1[ub(t1)]
        const float cy_h1 = bperm_f(r2b, inc);   // cy1[ub(t2)]

        const float wo0 = cy_h0 - cy_l0;   // w_outer[2l]
        const float wo1 = cy_h1 - cy_l1;   // w_outer[2l+1]

        const float d0 = fmaxf(0.0f, ww[r].x - wo0);
        const float d1 = fmaxf(0.0f, ww[r].y - wo1);
        res[r].x = d0 * d0 * __builtin_amdgcn_rcpf(ww[r].x + EPS);
        res[r].y = d1 * d1 * __builtin_amdgcn_rcpf(ww[r].y + EPS);
    }

    #pragma unroll
    for (int r = 0; r < ROWS; ++r) {
        float* o_row = out + (size_t)(row0 + r) * S;
        *reinterpret_cast<float2*>(o_row + 2 * lane) = res[r];
    }
}

}  // namespace

extern "C" void kernel_launch(void* const* d_in, const int* in_sizes, int n_in,
                              void* d_out, int out_size, void* d_ws, size_t ws_size,
                              hipStream_t stream) {
    const float* t     = (const float*)d_in[0];
    const float* w     = (const float*)d_in[1];
    const float* t_hat = (const float*)d_in[2];
    const float* w_hat = (const float*)d_in[3];
    float* out = (float*)d_out;

    const int N = in_sizes[1] / S;  // 262144
    proposal_loss_kernel<<<N / (4 * ROWS), 256, 0, stream>>>(t, w, t_hat, w_hat, out);
}

// Round 8
// 96.452 us; speedup vs baseline: 1.0424x; 1.0424x over previous
//
#include <hip/hip_runtime.h>

namespace {

constexpr int S = 128;   // fine bins per row
constexpr int P = 64;    // proposal bins per row
constexpr int ROWS = 4;  // rows per wave
constexpr float EPS = 1.1920928955078125e-07f;  // np.finfo(np.float32).eps

typedef float v2f __attribute__((ext_vector_type(2)));  // native vec for nt-store

// Crossbar read: value of `v` from lane (byteaddr/4 & 63). Conflict-free.
__device__ inline float bperm_f(int byteaddr, float v) {
    return __int_as_float(__builtin_amdgcn_ds_bpermute(byteaddr, __float_as_int(v)));
}

// v += dpp_permute(v); bound_ctrl=false, old=0 -> masked/invalid lanes add 0.
template <int CTRL, int ROW_MASK>
__device__ inline float dpp_add(float v) {
    int perm = __builtin_amdgcn_update_dpp(0, __float_as_int(v), CTRL, ROW_MASK, 0xf, false);
    return v + __int_as_float(perm);
}

template <int LANE>
__device__ inline float rdlane_f(float v) {
    return __int_as_float(__builtin_amdgcn_readlane(__float_as_int(v), LANE));
}

// One 64-lane wave per FOUR rows; all loads issued up-front, then 4
// independent compute chains. Stores are NONTEMPORAL (no L2/L3 allocate):
// the 134 MB output stream is never re-read, and letting it allocate evicts
// input lines that would otherwise hit in L3 on the next graph replay.
// Per row: lane l holds th1 = t_hat[l+1], inc = cy1[l+1] (inclusive scan).
// lower_bound counts over inner edges t_hat[1..64]; t in (0,1) keeps lb in
// [1,64]. Byte convention: element i+1 (t_hat or cy1) at lane i -> byte 4i.
__global__ __launch_bounds__(256) void proposal_loss_kernel(
    const float* __restrict__ t,      // [N, S+1]
    const float* __restrict__ w,      // [N, S]
    const float* __restrict__ t_hat,  // [N, P+1]
    const float* __restrict__ w_hat,  // [N, P]
    float* __restrict__ out)          // [N, S]
{
    const int wv   = threadIdx.x >> 6;
    const int lane = threadIdx.x & 63;
    const int row0 = (blockIdx.x << 2 | wv) * ROWS;

    float  th1[ROWS], wh[ROWS], tS[ROWS];
    float2 tt[ROWS], ww[ROWS];

    // ---- issue ALL loads first: ~4 KB of reads in flight per wave ----
    #pragma unroll
    for (int r = 0; r < ROWS; ++r) {
        const int row = row0 + r;
        const float* t_row  = t     + (size_t)row * (S + 1);
        const float* w_row  = w     + (size_t)row * S;
        const float* th_row = t_hat + (size_t)row * (P + 1);
        const float* wh_row = w_hat + (size_t)row * P;
        th1[r] = th_row[lane + 1];                              // t_hat[l+1]
        wh[r]  = wh_row[lane];
        tt[r]  = *reinterpret_cast<const float2*>(t_row + 2 * lane);
        ww[r]  = *reinterpret_cast<const float2*>(w_row + 2 * lane);
        tS[r]  = t_row[S];                                      // t[128], bcast
    }

    v2f res[ROWS];

    #pragma unroll
    for (int r = 0; r < ROWS; ++r) {
        // ---- inclusive scan of w_hat via DPP (VALU): inc(l) = cy1[l+1] ----
        float inc = wh[r];
        inc = dpp_add<0x111, 0xf>(inc);   // row_shr:1
        inc = dpp_add<0x112, 0xf>(inc);   // row_shr:2
        inc = dpp_add<0x114, 0xf>(inc);   // row_shr:4
        inc = dpp_add<0x118, 0xf>(inc);   // row_shr:8
        inc = dpp_add<0x142, 0xa>(inc);   // row_bcast:15 -> rows 1,3
        inc = dpp_add<0x143, 0xc>(inc);   // row_bcast:31 -> rows 2,3

        // ---- wave-uniform coarse table (SGPR): A[k]=t_hat[k+1] at lane k ----
        const float e31 = rdlane_f<31>(th1[r]);
        const float e15 = rdlane_f<15>(th1[r]);
        const float e47 = rdlane_f<47>(th1[r]);
        const float e7  = rdlane_f<7 >(th1[r]);
        const float e23 = rdlane_f<23>(th1[r]);
        const float e39 = rdlane_f<39>(th1[r]);
        const float e55 = rdlane_f<55>(th1[r]);

        // Branchless lower_bound: 3 coarse VALU levels + 3 fine ds_bpermute.
        // Returns posb = (lb-1)*4.
        auto lbb = [&](float v) {
            int posb = (e31 < v) ? 128 : 0;
            float l2 = posb ? e47 : e15;
            posb += (l2 < v) ? 64 : 0;
            float l3a = (posb & 128) ? e39 : e7;
            float l3b = (posb & 128) ? e55 : e23;
            float l3  = (posb & 64) ? l3b : l3a;
            posb += (l3 < v) ? 32 : 0;
            float p = bperm_f(posb + 12, th1[r]);  posb += (p < v) ? 16 : 0;
            p = bperm_f(posb + 4, th1[r]);         posb += (p < v) ? 8 : 0;
            p = bperm_f(posb, th1[r]);             posb += (p < v) ? 4 : 0;
            return posb;
        };

        const float t0  = tt[r].x;
        const float t1v = tt[r].y;
        const int b0 = lbb(t0);     // (lb(t[2l])-1)*4
        const int b1 = lbb(t1v);    // (lb(t[2l+1])-1)*4

        // Tie fixup via crossbar probe: ub = lb + (t_hat[lb] == v).
        const float p0 = bperm_f(b0, th1[r]);
        const float p1 = bperm_f(b1, th1[r]);
        const int u0b = b0 + ((p0 == t0)  ? 4 : 0);   // (ub(t0)-1)*4
        const int u1b = b1 + ((p1 == t1v) ? 4 : 0);   // (ub(t1)-1)*4

        // ub(t[2l+2]) = neighbor's ub(t0); lane 63 via ballot searchsorted:
        // ub(t[128]) byte = 4 * popc(t_hat[1..64] <= t[128]).
        int r2b = __shfl_down(u0b, 1, 64);
        const unsigned long long mS = __ballot(th1[r] <= tS[r]);
        const int pcb = (int)__popcll(mS) << 2;
        if (lane == 63) r2b = pcb;

        // cy1 gathers from the register-resident scan.
        const float cy_l0 = bperm_f(b0,  inc);   // cy1[lb(t0)]
        const float cy_l1 = bperm_f(b1,  inc);   // cy1[lb(t1)]
        const float cy_h0 = bperm_f(u1b, inc);   // cy1[ub(t1)]
        const float cy_h1 = bperm_f(r2b, inc);   // cy1[ub(t2)]

        const float wo0 = cy_h0 - cy_l0;   // w_outer[2l]
        const float wo1 = cy_h1 - cy_l1;   // w_outer[2l+1]

        const float d0 = fmaxf(0.0f, ww[r].x - wo0);
        const float d1 = fmaxf(0.0f, ww[r].y - wo1);
        res[r].x = d0 * d0 * __builtin_amdgcn_rcpf(ww[r].x + EPS);
        res[r].y = d1 * d1 * __builtin_amdgcn_rcpf(ww[r].y + EPS);
    }

    // ---- nontemporal stores: output never re-read; don't pollute L2/L3 ----
    #pragma unroll
    for (int r = 0; r < ROWS; ++r) {
        float* o_row = out + (size_t)(row0 + r) * S;
        __builtin_nontemporal_store(res[r], reinterpret_cast<v2f*>(o_row + 2 * lane));
    }
}

}  // namespace

extern "C" void kernel_launch(void* const* d_in, const int* in_sizes, int n_in,
                              void* d_out, int out_size, void* d_ws, size_t ws_size,
                              hipStream_t stream) {
    const float* t     = (const float*)d_in[0];
    const float* w     = (const float*)d_in[1];
    const float* t_hat = (const float*)d_in[2];
    const float* w_hat = (const float*)d_in[3];
    float* out = (float*)d_out;

    const int N = in_sizes[1] / S;  // 262144
    proposal_loss_kernel<<<N / (4 * ROWS), 256, 0, stream>>>(t, w, t_hat, w_hat, out);
}